// Round 5
// baseline (286.705 us; speedup 1.0000x reference)
//
#include <hip/hip_runtime.h>

// 2D Haar DWT, single level — LDS-staged, 16 KB-burst version.
// Input:  x (768 images of 512x512 fp32)
// Output: LL | LH | HL | HH, each 768 x 256 x 256 fp32, concatenated.
//
// Block = 512 threads owns a 32-row x 512-col input tile (64 KB) of one image.
// Phase 1: coalesced float4 NT loads + horizontal butterfly -> LDS (L/H planes).
// Phase 2: vertical butterfly from LDS -> each subband written as one 16 KB
//          contiguous burst per block (float4 NT stores).
//
// LL = 0.5(sA+sB), LH = 0.5(sA-sB), HL = 0.5(dA+dB), HH = 0.5(dA-dB)
// where sA=a+b, dA=a-b (even row), sB=c+d, dB=c-d (odd row).

#define IN_W       512
#define OUT_W      256
#define TILE_IROWS 32   // input rows per block
#define TILE_OROWS 16   // output rows per block
#define NTHREADS   512

typedef float f32x4 __attribute__((ext_vector_type(4)));
typedef float f32x2 __attribute__((ext_vector_type(2)));

__global__ __launch_bounds__(NTHREADS) void dwt2d_haar_kernel(
    const float* __restrict__ x,
    float* __restrict__ out,
    int n_img)
{
    __shared__ float Lh[TILE_IROWS][OUT_W];   // 32 KB: horizontal sums  (a+b)
    __shared__ float Hh[TILE_IROWS][OUT_W];   // 32 KB: horizontal diffs (a-b)

    const int bid  = blockIdx.x;
    const int img  = bid >> 4;      // 16 tiles per image (256 out rows / 16)
    const int tile = bid & 15;
    const int tid  = threadIdx.x;

    const float* src = x + (long long)img * (IN_W * IN_W)
                         + (long long)tile * (TILE_IROWS * IN_W);

    // ---- phase 1: load 64 KB tile (coalesced float4), horizontal butterfly ----
#pragma unroll
    for (int k = 0; k < 8; ++k) {
        const int f  = tid + k * NTHREADS; // float4 index in tile, 0..4095
        const int r  = f >> 7;             // input row within tile, 0..31
        const int c4 = f & 127;            // float4-col, 0..127
        const f32x4 v = __builtin_nontemporal_load(
            reinterpret_cast<const f32x4*>(src + (long long)f * 4));
        f32x2 s, d;
        s.x = v.x + v.y; d.x = v.x - v.y;
        s.y = v.z + v.w; d.y = v.z - v.w;
        *reinterpret_cast<f32x2*>(&Lh[r][c4 * 2]) = s;
        *reinterpret_cast<f32x2*>(&Hh[r][c4 * 2]) = d;
    }
    __syncthreads();

    // ---- phase 2: vertical butterfly, 16 KB contiguous burst per subband ----
    const long long sub = (long long)n_img * (OUT_W * OUT_W);
    float* __restrict__ ll = out;
    float* __restrict__ lh = out + sub;
    float* __restrict__ hl = out + 2 * sub;
    float* __restrict__ hh = out + 3 * sub;
    const long long obase = (long long)img * (OUT_W * OUT_W)
                          + (long long)tile * (TILE_OROWS * OUT_W);

#pragma unroll
    for (int k = 0; k < 2; ++k) {
        const int g    = tid + k * NTHREADS; // float4 index in output tile, 0..1023
        const int orow = g >> 6;             // output row within tile, 0..15
        const int c4   = g & 63;             // float4-col, 0..63
        const f32x4 L0 = *reinterpret_cast<const f32x4*>(&Lh[2 * orow][c4 * 4]);
        const f32x4 L1 = *reinterpret_cast<const f32x4*>(&Lh[2 * orow + 1][c4 * 4]);
        const f32x4 H0 = *reinterpret_cast<const f32x4*>(&Hh[2 * orow][c4 * 4]);
        const f32x4 H1 = *reinterpret_cast<const f32x4*>(&Hh[2 * orow + 1][c4 * 4]);
        const long long o = obase + (long long)g * 4;
        __builtin_nontemporal_store(0.5f * (L0 + L1), reinterpret_cast<f32x4*>(ll + o));
        __builtin_nontemporal_store(0.5f * (L0 - L1), reinterpret_cast<f32x4*>(lh + o));
        __builtin_nontemporal_store(0.5f * (H0 + H1), reinterpret_cast<f32x4*>(hl + o));
        __builtin_nontemporal_store(0.5f * (H0 - H1), reinterpret_cast<f32x4*>(hh + o));
    }
}

extern "C" void kernel_launch(void* const* d_in, const int* in_sizes, int n_in,
                              void* d_out, int out_size, void* d_ws, size_t ws_size,
                              hipStream_t stream) {
    const float* x = (const float*)d_in[0];
    float* out = (float*)d_out;

    const int n_img  = in_sizes[0] / (IN_W * IN_W);  // 8*96 = 768
    const int blocks = n_img * 16;                   // 16 tiles per image

    dwt2d_haar_kernel<<<dim3(blocks), dim3(NTHREADS), 0, stream>>>(x, out, n_img);
}

// Round 6
// 284.461 us; speedup vs baseline: 1.0079x; 1.0079x over previous
//
#include <hip/hip_runtime.h>

// 2D Haar DWT, single level — LDS-staged long-burst version (best: R4, 280 µs).
// Input:  x (768 images of 512x512 fp32)
// Output: LL | LH | HL | HH, each 768 x 256 x 256 fp32, concatenated.
//
// Block = 256 threads owns a 16-row x 512-col input tile (32 KB) of one image.
// Phase 1: coalesced float4 NT loads + horizontal butterfly -> LDS (L/H planes).
// Phase 2: vertical butterfly from LDS -> each subband written as one 8 KB
//          contiguous burst per block (float4 NT stores).
// 32 KB LDS @ 256 thr -> 5 blocks/CU = 20 waves/CU (R5's 64 KB/512 thr variant
// dropped to 16 waves/CU and regressed 2.4% — 8 KB burst is the sweet spot).
//
// LL = 0.5(sA+sB), LH = 0.5(sA-sB), HL = 0.5(dA+dB), HH = 0.5(dA-dB)
// where sA=a+b, dA=a-b (even row), sB=c+d, dB=c-d (odd row).

#define IN_W       512
#define OUT_W      256
#define TILE_IROWS 16   // input rows per block
#define TILE_OROWS 8    // output rows per block

typedef float f32x4 __attribute__((ext_vector_type(4)));
typedef float f32x2 __attribute__((ext_vector_type(2)));

__global__ __launch_bounds__(256) void dwt2d_haar_kernel(
    const float* __restrict__ x,
    float* __restrict__ out,
    int n_img)
{
    __shared__ float Lh[TILE_IROWS][OUT_W];   // 16 KB: horizontal sums  (a+b)
    __shared__ float Hh[TILE_IROWS][OUT_W];   // 16 KB: horizontal diffs (a-b)

    const int bid  = blockIdx.x;
    const int img  = bid >> 5;      // 32 tiles per image (256 out rows / 8)
    const int tile = bid & 31;
    const int tid  = threadIdx.x;

    const float* src = x + (long long)img * (IN_W * IN_W)
                         + (long long)tile * (TILE_IROWS * IN_W);

    // ---- phase 1: load 32 KB tile (coalesced float4), horizontal butterfly ----
#pragma unroll
    for (int k = 0; k < 8; ++k) {
        const int f  = tid + k * 256;   // float4 index in tile, 0..2047
        const int r  = f >> 7;          // input row within tile, 0..15
        const int c4 = f & 127;         // float4-col, 0..127
        const f32x4 v = __builtin_nontemporal_load(
            reinterpret_cast<const f32x4*>(src + (long long)f * 4));
        f32x2 s, d;
        s.x = v.x + v.y; d.x = v.x - v.y;
        s.y = v.z + v.w; d.y = v.z - v.w;
        *reinterpret_cast<f32x2*>(&Lh[r][c4 * 2]) = s;
        *reinterpret_cast<f32x2*>(&Hh[r][c4 * 2]) = d;
    }
    __syncthreads();

    // ---- phase 2: vertical butterfly, 8 KB contiguous burst per subband ----
    const long long sub = (long long)n_img * (OUT_W * OUT_W);
    float* __restrict__ ll = out;
    float* __restrict__ lh = out + sub;
    float* __restrict__ hl = out + 2 * sub;
    float* __restrict__ hh = out + 3 * sub;
    const long long obase = (long long)img * (OUT_W * OUT_W)
                          + (long long)tile * (TILE_OROWS * OUT_W);

#pragma unroll
    for (int k = 0; k < 2; ++k) {
        const int g    = tid + k * 256; // float4 index in output tile, 0..511
        const int orow = g >> 6;        // output row within tile, 0..7
        const int c4   = g & 63;        // float4-col, 0..63
        const f32x4 L0 = *reinterpret_cast<const f32x4*>(&Lh[2 * orow][c4 * 4]);
        const f32x4 L1 = *reinterpret_cast<const f32x4*>(&Lh[2 * orow + 1][c4 * 4]);
        const f32x4 H0 = *reinterpret_cast<const f32x4*>(&Hh[2 * orow][c4 * 4]);
        const f32x4 H1 = *reinterpret_cast<const f32x4*>(&Hh[2 * orow + 1][c4 * 4]);
        const long long o = obase + (long long)g * 4;
        __builtin_nontemporal_store(0.5f * (L0 + L1), reinterpret_cast<f32x4*>(ll + o));
        __builtin_nontemporal_store(0.5f * (L0 - L1), reinterpret_cast<f32x4*>(lh + o));
        __builtin_nontemporal_store(0.5f * (H0 + H1), reinterpret_cast<f32x4*>(hl + o));
        __builtin_nontemporal_store(0.5f * (H0 - H1), reinterpret_cast<f32x4*>(hh + o));
    }
}

extern "C" void kernel_launch(void* const* d_in, const int* in_sizes, int n_in,
                              void* d_out, int out_size, void* d_ws, size_t ws_size,
                              hipStream_t stream) {
    const float* x = (const float*)d_in[0];
    float* out = (float*)d_out;

    const int n_img  = in_sizes[0] / (IN_W * IN_W);  // 8*96 = 768
    const int blocks = n_img * 32;                   // 32 tiles per image

    dwt2d_haar_kernel<<<dim3(blocks), dim3(256), 0, stream>>>(x, out, n_img);
}